// Round 1
// baseline (132.159 us; speedup 1.0000x reference)
//
#include <hip/hip_runtime.h>
#include <cstdint>
#include <cstddef>

#define N_Q 4096
#define M_K 16384
#define LNB 96
#define CH  512
#define NH  8

typedef _Float16 half8  __attribute__((ext_vector_type(8)));
typedef _Float16 half4v __attribute__((ext_vector_type(4)));
typedef _Float16 half2v __attribute__((ext_vector_type(2)));
typedef float    floatx4 __attribute__((ext_vector_type(4)));

__device__ __forceinline__ void async16(const void* g, void* l) {
    __builtin_amdgcn_global_load_lds(
        (const __attribute__((address_space(1))) void*)g,
        (__attribute__((address_space(3))) void*)l, 16, 0, 0);
}

// ---------------- fp32 -> fp16 convert (4 elems/thread, exact grid) ----------------
__global__ void cvt_f32_f16(const float* __restrict__ src, _Float16* __restrict__ dst) {
    size_t i = (size_t)blockIdx.x * blockDim.x + threadIdx.x;
    float4 v = ((const float4*)src)[i];
    half4v o;
    o[0] = (_Float16)v.x; o[1] = (_Float16)v.y;
    o[2] = (_Float16)v.z; o[3] = (_Float16)v.w;
    ((half4v*)dst)[i] = o;
}

// ---------------- fp16 GEMM: out[i][j] = (sum_k A[i][k]*Bw[j][k] + bias[j]) * oscale
// A: [rows][512] fp16, Bw: [128*gridDim.y][512] fp16 rows, out fp16 or fp32.
// 128x128 tile, BK=32, 256 threads (4 waves, each 64x64 of 16x16x32 frags).
template<int OUTF16>
__global__ __launch_bounds__(256) void gemm_f16(
    const _Float16* __restrict__ A, const _Float16* __restrict__ Bw,
    const float* __restrict__ bias, void* __restrict__ outp, float oscale)
{
    __shared__ alignas(16) _Float16 As[128 * 32];
    __shared__ alignas(16) _Float16 Bs[128 * 32];

    const int t    = threadIdx.x;
    const int lane = t & 63;
    const int wave = t >> 6;
    const int wm   = wave >> 1, wn = wave & 1;
    const int bm   = blockIdx.x, bn = blockIdx.y;

    floatx4 acc[4][4] = {};

    const int rowL = t >> 2;          // 0..63
    const int kcol = (t & 3) * 8;     // 0,8,16,24
    const _Float16* gA = A  + (size_t)(bm * 128 + rowL) * CH + kcol;
    const _Float16* gB = Bw + (size_t)(bn * 128 + rowL) * CH + kcol;
    _Float16* lA = &As[rowL * 32 + kcol];
    _Float16* lB = &Bs[rowL * 32 + kcol];

    const int r0 = lane & 15;
    const int ko = (lane >> 4) * 8;

    for (int kt = 0; kt < CH / 32; ++kt) {
        const _Float16* a0 = gA + kt * 32;
        const _Float16* b0 = gB + kt * 32;
        async16(a0,            lA);
        async16(a0 + 64 * CH,  lA + 64 * 32);
        async16(b0,            lB);
        async16(b0 + 64 * CH,  lB + 64 * 32);
        __syncthreads();   // compiler emits vmcnt(0) drain before barrier

        half8 af[4], bf[4];
        #pragma unroll
        for (int mi = 0; mi < 4; ++mi)
            af[mi] = *(const half8*)&As[(wm * 64 + mi * 16 + r0) * 32 + ko];
        #pragma unroll
        for (int ni = 0; ni < 4; ++ni)
            bf[ni] = *(const half8*)&Bs[(wn * 64 + ni * 16 + r0) * 32 + ko];
        #pragma unroll
        for (int mi = 0; mi < 4; ++mi)
            #pragma unroll
            for (int ni = 0; ni < 4; ++ni)
                acc[mi][ni] = __builtin_amdgcn_mfma_f32_16x16x32_f16(
                    af[mi], bf[ni], acc[mi][ni], 0, 0, 0);
        __syncthreads();
    }

    // epilogue: C/D layout col=lane&15, row=(lane>>4)*4+r  [m89-verified]
    #pragma unroll
    for (int mi = 0; mi < 4; ++mi) {
        #pragma unroll
        for (int ni = 0; ni < 4; ++ni) {
            const int col = bn * 128 + wn * 64 + ni * 16 + (lane & 15);
            const float bv = bias[col];
            #pragma unroll
            for (int r = 0; r < 4; ++r) {
                const int row = bm * 128 + wm * 64 + mi * 16 + (lane >> 4) * 4 + r;
                const float v = (acc[mi][ni][r] + bv) * oscale;
                if (OUTF16) ((_Float16*)outp)[(size_t)row * CH + col] = (_Float16)v;
                else        ((float*)outp)[(size_t)row * CH + col]    = v;
            }
        }
    }
}

// ---------------- local attention: one block per query ----------------
// q16 already has the 1/sqrt(Dh) scaling folded in (GEMM epilogue oscale).
__global__ __launch_bounds__(256) void attn_kernel(
    const _Float16* __restrict__ q16, const _Float16* __restrict__ k16,
    const _Float16* __restrict__ v16, const int* __restrict__ ipair,
    const int* __restrict__ ibatch, const int* __restrict__ kcnt,
    _Float16* __restrict__ op16, float* __restrict__ aout)
{
    __shared__ alignas(16) _Float16 qs[CH];
    __shared__ int   gix[LNB];
    __shared__ float pls[LNB * NH];

    const int t = threadIdx.x;
    // XCD swizzle: batch b (= n/512) -> XCD b, so each XCD's L2 holds one
    // batch's K+V fp16 slab (2MB + 2MB = 4MB = one XCD L2).
    const int n = ((blockIdx.x & 7) << 9) | (blockIdx.x >> 3);

    // load q row (512 fp16) into LDS
    *(uint32_t*)&qs[t * 2] = *(const uint32_t*)&q16[(size_t)n * CH + t * 2];
    if (t < LNB) {
        const int idx = ipair[(size_t)n * LNB + t];
        const int b   = ibatch[n];
        int off = 0;
        for (int i = 0; i < b; ++i) off += kcnt[i];
        gix[t] = (idx < 0) ? -1 : (idx + off);
    }
    __syncthreads();

    // phase 1: logits.  lane -> head h = lane/8, dims [ (lane&7)*8 .. +8 ) of that head
    const int lane = t & 63, wv = t >> 6;
    const half8 qv = *(const half8*)&qs[lane * 8];
    float qf[8];
    #pragma unroll
    for (int j = 0; j < 8; ++j) qf[j] = (float)qv[j];

    for (int l = wv; l < LNB; l += 4) {
        const int gg = gix[l];
        const int g  = gg < 0 ? 0 : gg;
        const half8 kv = *(const half8*)(k16 + (size_t)g * CH + lane * 8);
        float part = 0.f;
        #pragma unroll
        for (int j = 0; j < 8; ++j) part = fmaf(qf[j], (float)kv[j], part);
        part += __shfl_xor(part, 1);
        part += __shfl_xor(part, 2);
        part += __shfl_xor(part, 4);
        if ((lane & 7) == 0)
            pls[l * NH + (lane >> 3)] = (gg < 0) ? -1e30f : part;
    }
    __syncthreads();

    // phase 2: softmax over L per head.  thread t: h = t>>5, j = t&31 covers l = j, j+32, j+64
    {
        const int h = t >> 5, j = t & 31;
        const float v0 = pls[j * NH + h];
        const float v1 = pls[(j + 32) * NH + h];
        const float v2 = pls[(j + 64) * NH + h];
        float m = fmaxf(v0, fmaxf(v1, v2));
        #pragma unroll
        for (int s = 16; s >= 1; s >>= 1) m = fmaxf(m, __shfl_xor(m, s, 32));
        const float e0 = expf(v0 - m), e1 = expf(v1 - m), e2 = expf(v2 - m);
        float ssum = e0 + e1 + e2;
        #pragma unroll
        for (int s = 16; s >= 1; s >>= 1) ssum += __shfl_xor(ssum, s, 32);
        const float rinv = 1.0f / ssum;
        // each (l,h) slot read & written only by this thread -> no barrier needed
        pls[j * NH + h]        = e0 * rinv;
        pls[(j + 32) * NH + h] = e1 * rinv;
        pls[(j + 64) * NH + h] = e2 * rinv;
    }
    __syncthreads();

    // attn_mean output (second output of the reference)
    if (t < LNB) {
        float s = 0.f;
        #pragma unroll
        for (int h = 0; h < NH; ++h) s += pls[t * NH + h];
        aout[(size_t)n * LNB + t] = s * (1.0f / NH);
    }

    // phase 3: PV.  thread t owns output dims c0=2t, 2t+1 (head h = t>>5).
    {
        const int c0 = t * 2;
        const int h  = t >> 5;
        float a0 = 0.f, a1 = 0.f;
        for (int l = 0; l < LNB; ++l) {
            const int gg = gix[l];
            const int g  = gg < 0 ? 0 : gg;   // p==0 for masked -> exact
            const float p = pls[l * NH + h];
            const half2v vv = *(const half2v*)(v16 + (size_t)g * CH + c0);
            a0 = fmaf(p, (float)vv[0], a0);
            a1 = fmaf(p, (float)vv[1], a1);
        }
        half2v o; o[0] = (_Float16)a0; o[1] = (_Float16)a1;
        *(half2v*)&op16[(size_t)n * CH + c0] = o;
    }
}

extern "C" void kernel_launch(void* const* d_in, const int* in_sizes, int n_in,
                              void* d_out, int out_size, void* d_ws, size_t ws_size,
                              hipStream_t stream)
{
    const float* query = (const float*)d_in[0];
    const float* key   = (const float*)d_in[1];
    const float* value = (const float*)d_in[2];
    const int*   ipair = (const int*)d_in[3];
    const int*   kcnt  = (const int*)d_in[5];
    const int*   ibat  = (const int*)d_in[6];
    const float* wIn   = (const float*)d_in[7];
    const float* bIn   = (const float*)d_in[8];
    const float* wOut  = (const float*)d_in[9];
    const float* bOut  = (const float*)d_in[10];

    float* out  = (float*)d_out;
    float* aout = out + (size_t)N_Q * CH;   // second output: attn mean (4096x96)

    char* ws = (char*)d_ws;
    _Float16* w16  = (_Float16*)(ws);                // 1536*512*2 = 1572864
    _Float16* wo16 = (_Float16*)(ws + 1572864);      //  512*512*2 =  524288
    _Float16* qx16 = (_Float16*)(ws + 2097152);      // 4096*512*2 = 4194304
    _Float16* kx16 = (_Float16*)(ws + 6291456);      // 16384*512*2
    _Float16* vx16 = (_Float16*)(ws + 23068672);
    _Float16* q16  = (_Float16*)(ws + 39845888);
    _Float16* k16  = (_Float16*)(ws + 44040192);
    _Float16* v16  = (_Float16*)(ws + 60817408);
    _Float16* op16 = (_Float16*)(ws + 77594624);     // total ~81.8 MB

    // fp32 -> fp16 conversions (each thread = 4 elems, all sizes % 1024 == 0)
    cvt_f32_f16<<<2048, 256, 0, stream>>>(query, qx16);
    cvt_f32_f16<<<8192, 256, 0, stream>>>(key,   kx16);
    cvt_f32_f16<<<8192, 256, 0, stream>>>(value, vx16);
    cvt_f32_f16<<<768,  256, 0, stream>>>(wIn,   w16);
    cvt_f32_f16<<<256,  256, 0, stream>>>(wOut,  wo16);

    // QKV projections (q gets the 1/sqrt(64)=0.125 scaling in the epilogue)
    gemm_f16<1><<<dim3(32, 4),  256, 0, stream>>>(qx16, w16,                   bIn,        q16, 0.125f);
    gemm_f16<1><<<dim3(128, 4), 256, 0, stream>>>(kx16, w16 + (size_t)512*512, bIn + 512,  k16, 1.0f);
    gemm_f16<1><<<dim3(128, 4), 256, 0, stream>>>(vx16, w16 + (size_t)1024*512,bIn + 1024, v16, 1.0f);

    // local attention (one block per query, XCD-swizzled for K/V L2 residency)
    attn_kernel<<<4096, 256, 0, stream>>>(q16, k16, v16, ipair, ibat, kcnt, op16, aout);

    // output projection -> fp32 d_out
    gemm_f16<0><<<dim3(32, 4), 256, 0, stream>>>(op16, wo16, bOut, d_out, 1.0f);
}

// Round 2
// 120.394 us; speedup vs baseline: 1.0977x; 1.0977x over previous
//
#include <hip/hip_runtime.h>
#include <cstdint>
#include <cstddef>

#define N_Q 4096
#define M_K 16384
#define LNB 96
#define CH  512
#define NH  8

typedef _Float16 half8  __attribute__((ext_vector_type(8)));
typedef _Float16 half4v __attribute__((ext_vector_type(4)));
typedef _Float16 half2v __attribute__((ext_vector_type(2)));
typedef float    floatx4 __attribute__((ext_vector_type(4)));
typedef float    floatx2 __attribute__((ext_vector_type(2)));

__device__ __forceinline__ void async16(const void* g, void* l) {
    __builtin_amdgcn_global_load_lds(
        (const __attribute__((address_space(1))) void*)g,
        (__attribute__((address_space(3))) void*)l, 16, 0, 0);
}

// DPP butterfly add over an 8-lane octet: xor1 (quad_perm[1,0,3,2]=0xB1),
// xor2 (quad_perm[2,3,0,1]=0x4E), row_half_mirror (0x141). Pure VALU.
template<int CTRL>
__device__ __forceinline__ float dpp_addf(float x) {
    int xi = __builtin_bit_cast(int, x);
    int yi = __builtin_amdgcn_update_dpp(xi, xi, CTRL, 0xF, 0xF, false);
    return x + __builtin_bit_cast(float, yi);
}
__device__ __forceinline__ float octet_sum(float x) {
    x = dpp_addf<0x141>(x);   // l <-> 7-l within 8
    x = dpp_addf<0x4E>(x);    // xor 2
    x = dpp_addf<0xB1>(x);    // xor 1
    return x;
}

// ---------------- fp32 -> fp16 convert ----------------
__global__ void cvt_f32_f16(const float* __restrict__ src, _Float16* __restrict__ dst) {
    size_t i = (size_t)blockIdx.x * blockDim.x + threadIdx.x;
    float4 v = ((const float4*)src)[i];
    half4v o;
    o[0] = (_Float16)v.x; o[1] = (_Float16)v.y;
    o[2] = (_Float16)v.z; o[3] = (_Float16)v.w;
    ((half4v*)dst)[i] = o;
}

// ---------------- fp16 GEMM, tile TM x 128, BK=32, 256 threads ----------------
template<int OUTF16, int TM>
__global__ __launch_bounds__(256) void gemm_f16(
    const _Float16* __restrict__ A, const _Float16* __restrict__ Bw,
    const float* __restrict__ bias, void* __restrict__ outp, float oscale)
{
    constexpr int MI = TM / 32;             // 16-row frags per wave (M)
    __shared__ alignas(16) _Float16 As[TM * 32];
    __shared__ alignas(16) _Float16 Bs[128 * 32];

    const int t    = threadIdx.x;
    const int lane = t & 63;
    const int wave = t >> 6;
    const int wm   = wave >> 1, wn = wave & 1;
    const int bm   = blockIdx.x, bn = blockIdx.y;

    floatx4 acc[MI][4] = {};

    const int rowL = t >> 2;          // 0..63
    const int kcol = (t & 3) * 8;     // 0,8,16,24
    const _Float16* gA = A  + (size_t)(bm * TM  + rowL) * CH + kcol;
    const _Float16* gB = Bw + (size_t)(bn * 128 + rowL) * CH + kcol;
    _Float16* lA = &As[rowL * 32 + kcol];
    _Float16* lB = &Bs[rowL * 32 + kcol];

    const int r0 = lane & 15;
    const int ko = (lane >> 4) * 8;

    for (int kt = 0; kt < CH / 32; ++kt) {
        const _Float16* a0 = gA + kt * 32;
        const _Float16* b0 = gB + kt * 32;
        async16(a0, lA);
        if constexpr (TM == 128) async16(a0 + 64 * CH, lA + 64 * 32);
        async16(b0,           lB);
        async16(b0 + 64 * CH, lB + 64 * 32);
        __syncthreads();

        half8 af[MI], bf[4];
        #pragma unroll
        for (int mi = 0; mi < MI; ++mi)
            af[mi] = *(const half8*)&As[(wm * (TM / 2) + mi * 16 + r0) * 32 + ko];
        #pragma unroll
        for (int ni = 0; ni < 4; ++ni)
            bf[ni] = *(const half8*)&Bs[(wn * 64 + ni * 16 + r0) * 32 + ko];
        #pragma unroll
        for (int mi = 0; mi < MI; ++mi)
            #pragma unroll
            for (int ni = 0; ni < 4; ++ni)
                acc[mi][ni] = __builtin_amdgcn_mfma_f32_16x16x32_f16(
                    af[mi], bf[ni], acc[mi][ni], 0, 0, 0);
        __syncthreads();
    }

    #pragma unroll
    for (int mi = 0; mi < MI; ++mi) {
        #pragma unroll
        for (int ni = 0; ni < 4; ++ni) {
            const int col = bn * 128 + wn * 64 + ni * 16 + (lane & 15);
            const float bv = bias[col];
            #pragma unroll
            for (int r = 0; r < 4; ++r) {
                const int row = bm * TM + wm * (TM / 2) + mi * 16 + (lane >> 4) * 4 + r;
                const float v = (acc[mi][ni][r] + bv) * oscale;
                if (OUTF16) ((_Float16*)outp)[(size_t)row * CH + col] = (_Float16)v;
                else        ((float*)outp)[(size_t)row * CH + col]    = v;
            }
        }
    }
}

// ---------------- local attention: one block (256 thr) per query ----------------
__global__ __launch_bounds__(256) void attn_kernel(
    const _Float16* __restrict__ q16, const _Float16* __restrict__ k16,
    const _Float16* __restrict__ v16, const int* __restrict__ ipair,
    const int* __restrict__ ibatch, const int* __restrict__ kcnt,
    _Float16* __restrict__ op16, float* __restrict__ aout)
{
    __shared__ uint32_t vmask[LNB];       // clamped row byte-offset | (masked<<31)
    __shared__ float    pls[LNB * 9];     // logits/probs, stride 9 (odd)
    __shared__ float    part[4][CH];      // per-wave PV partials

    const int t = threadIdx.x;
    // XCD swizzle: batch b = n/512 -> XCD b (K/V slab of one batch fits one L2)
    const int n = ((blockIdx.x & 7) << 9) | (blockIdx.x >> 3);

    if (t < LNB) {
        const int idx = ipair[(size_t)n * LNB + t];
        const int b   = ibatch[n];
        int off = 0;
        for (int i = 0; i < b; ++i) off += kcnt[i];
        const uint32_t vo = (uint32_t)((idx < 0 ? 0 : (idx + off)) * (CH * 2));
        vmask[t] = vo | (idx < 0 ? 0x80000000u : 0u);
    }
    __syncthreads();

    const int lane = t & 63, wv = t >> 6;
    const int h    = lane >> 3;           // head for this lane (phases 1 & 3)

    // ---- phase 1: logits. lane owns dims [lane*8, lane*8+8); octet = one head.
    {
        const half8 qv = *(const half8*)(q16 + (size_t)n * CH + lane * 8);
        for (int l = wv; l < LNB; l += 4) {
            const uint32_t vm = vmask[l];
            const uint32_t vo = vm & 0x7fffffffu;
            const half8 kv = *(const half8*)((const char*)k16 + vo + lane * 16);
            float acc = 0.f;
            #pragma unroll
            for (int u = 0; u < 8; ++u)
                acc = fmaf((float)qv[u], (float)kv[u], acc);
            acc = octet_sum(acc);
            if ((lane & 7) == 0)
                pls[l * 9 + h] = (vm & 0x80000000u) ? -1e30f : acc;
        }
    }
    __syncthreads();

    // ---- phase 2: softmax over L per head. thread (hh = t>>5, j = t&31)
    {
        const int hh = t >> 5, j = t & 31;
        const float v0 = pls[j * 9 + hh];
        const float v1 = pls[(j + 32) * 9 + hh];
        const float v2 = pls[(j + 64) * 9 + hh];
        float m = fmaxf(v0, fmaxf(v1, v2));
        #pragma unroll
        for (int s = 16; s >= 1; s >>= 1) m = fmaxf(m, __shfl_xor(m, s, 32));
        const float e0 = expf(v0 - m), e1 = expf(v1 - m), e2 = expf(v2 - m);
        float ssum = e0 + e1 + e2;
        #pragma unroll
        for (int s = 16; s >= 1; s >>= 1) ssum += __shfl_xor(ssum, s, 32);
        const float rinv = 1.0f / ssum;
        pls[j * 9 + hh]        = e0 * rinv;
        pls[(j + 32) * 9 + hh] = e1 * rinv;
        pls[(j + 64) * 9 + hh] = e2 * rinv;
    }
    __syncthreads();

    // ---- attn_mean (output 1)
    if (t < LNB) {
        float s = 0.f;
        #pragma unroll
        for (int u = 0; u < NH; ++u) s += pls[t * 9 + u];
        aout[(size_t)n * LNB + t] = s * (1.0f / NH);
    }

    // ---- phase 3: PV. wave wv owns l-chunk [wv*24, wv*24+24), lane owns 8 dims.
    {
        float acc[8] = {};
        const int l0 = wv * 24;
        #pragma unroll 4
        for (int l = l0; l < l0 + 24; ++l) {
            const uint32_t vo = vmask[l] & 0x7fffffffu;
            const float p = pls[l * 9 + h];
            const half8 vv = *(const half8*)((const char*)v16 + vo + lane * 16);
            #pragma unroll
            for (int u = 0; u < 8; ++u)
                acc[u] = fmaf(p, (float)vv[u], acc[u]);
        }
        floatx4 lo, hi;
        #pragma unroll
        for (int u = 0; u < 4; ++u) { lo[u] = acc[u]; hi[u] = acc[u + 4]; }
        *(floatx4*)&part[wv][lane * 8]     = lo;
        *(floatx4*)&part[wv][lane * 8 + 4] = hi;
    }
    __syncthreads();

    // ---- final cross-wave reduce: thread t owns dims 2t, 2t+1
    {
        const int c = t * 2;
        floatx2 s = *(const floatx2*)&part[0][c];
        #pragma unroll
        for (int w = 1; w < 4; ++w) {
            floatx2 pw = *(const floatx2*)&part[w][c];
            s[0] += pw[0]; s[1] += pw[1];
        }
        half2v o; o[0] = (_Float16)s[0]; o[1] = (_Float16)s[1];
        *(half2v*)&op16[(size_t)n * CH + c] = o;
    }
}

extern "C" void kernel_launch(void* const* d_in, const int* in_sizes, int n_in,
                              void* d_out, int out_size, void* d_ws, size_t ws_size,
                              hipStream_t stream)
{
    const float* query = (const float*)d_in[0];
    const float* key   = (const float*)d_in[1];
    const float* value = (const float*)d_in[2];
    const int*   ipair = (const int*)d_in[3];
    const int*   kcnt  = (const int*)d_in[5];
    const int*   ibat  = (const int*)d_in[6];
    const float* wIn   = (const float*)d_in[7];
    const float* bIn   = (const float*)d_in[8];
    const float* wOut  = (const float*)d_in[9];
    const float* bOut  = (const float*)d_in[10];

    float* out  = (float*)d_out;
    float* aout = out + (size_t)N_Q * CH;

    char* ws = (char*)d_ws;
    _Float16* w16  = (_Float16*)(ws);
    _Float16* wo16 = (_Float16*)(ws + 1572864);
    _Float16* qx16 = (_Float16*)(ws + 2097152);
    _Float16* kx16 = (_Float16*)(ws + 6291456);
    _Float16* vx16 = (_Float16*)(ws + 23068672);
    _Float16* q16  = (_Float16*)(ws + 39845888);
    _Float16* k16  = (_Float16*)(ws + 44040192);
    _Float16* v16  = (_Float16*)(ws + 60817408);
    _Float16* op16 = (_Float16*)(ws + 77594624);

    cvt_f32_f16<<<2048, 256, 0, stream>>>(query, qx16);
    cvt_f32_f16<<<8192, 256, 0, stream>>>(key,   kx16);
    cvt_f32_f16<<<8192, 256, 0, stream>>>(value, vx16);
    cvt_f32_f16<<<768,  256, 0, stream>>>(wIn,   w16);
    cvt_f32_f16<<<256,  256, 0, stream>>>(wOut,  wo16);

    gemm_f16<1, 64> <<<dim3(64, 4),  256, 0, stream>>>(qx16, w16,                    bIn,        q16, 0.125f);
    gemm_f16<1, 128><<<dim3(128, 4), 256, 0, stream>>>(kx16, w16 + (size_t)512*512,  bIn + 512,  k16, 1.0f);
    gemm_f16<1, 128><<<dim3(128, 4), 256, 0, stream>>>(vx16, w16 + (size_t)1024*512, bIn + 1024, v16, 1.0f);

    attn_kernel<<<4096, 256, 0, stream>>>(q16, k16, v16, ipair, ibat, kcnt, op16, aout);

    gemm_f16<0, 64><<<dim3(64, 4), 256, 0, stream>>>(op16, wo16, bOut, d_out, 1.0f);
}

// Round 4
// 113.790 us; speedup vs baseline: 1.1614x; 1.0580x over previous
//
#include <hip/hip_runtime.h>
#include <hip/hip_fp16.h>
#include <cstdint>
#include <cstddef>

#define N_Q 4096
#define M_K 16384
#define LNB 96
#define CH  512
#define NH  8

typedef _Float16 half8  __attribute__((ext_vector_type(8)));
typedef _Float16 h2     __attribute__((ext_vector_type(2)));
typedef float    floatx4 __attribute__((ext_vector_type(4)));
typedef float    floatx2 __attribute__((ext_vector_type(2)));

union H8 { half8 v; h2 p[4]; };

__device__ __forceinline__ h2 cvt2(float a, float b) {
    return __builtin_bit_cast(h2, __builtin_amdgcn_cvt_pkrtz(a, b));
}

__device__ __forceinline__ void async16(const void* g, void* l) {
    __builtin_amdgcn_global_load_lds(
        (const __attribute__((address_space(1))) void*)g,
        (__attribute__((address_space(3))) void*)l, 16, 0, 0);
}

// DPP butterfly add over an 8-lane octet (pure VALU).
template<int CTRL>
__device__ __forceinline__ float dpp_addf(float x) {
    int xi = __builtin_bit_cast(int, x);
    int yi = __builtin_amdgcn_update_dpp(xi, xi, CTRL, 0xF, 0xF, false);
    return x + __builtin_bit_cast(float, yi);
}
__device__ __forceinline__ float octet_sum(float x) {
    x = dpp_addf<0x141>(x);   // row_half_mirror
    x = dpp_addf<0x4E>(x);    // quad xor2
    x = dpp_addf<0xB1>(x);    // quad xor1
    return x;
}

// ---------------- fused weight convert: wIn (786432 f) ++ wOut (262144 f) -> fp16
__global__ void cvt_weights(const float* __restrict__ wIn, const float* __restrict__ wOut,
                            _Float16* __restrict__ dst) {
    const size_t i = (size_t)blockIdx.x * blockDim.x + threadIdx.x;   // float4 index
    const float4 v = (i < 196608) ? ((const float4*)wIn)[i]
                                  : ((const float4*)wOut)[i - 196608];
    h2 a = cvt2(v.x, v.y);
    h2 b = cvt2(v.z, v.w);
    *(h2*)&dst[i * 4]     = a;
    *(h2*)&dst[i * 4 + 2] = b;
}

// ---------------- GEMM body: out[i][j] = (sum_k A[i][k]*Bw[j][k] + bias[j]) * oscale
// A fp32 (AFP32=1, converted in-register) or fp16 (async16). 256 threads, BK=32.
template<int OUTF16, int TM, int AFP32>
__device__ __forceinline__ void gemm_body(
    const void* __restrict__ Ap, const _Float16* __restrict__ Bw,
    const float* __restrict__ bias, void* __restrict__ outp, float oscale,
    int bm, int bn)
{
    constexpr int MI = TM / 32;
    __shared__ alignas(16) _Float16 As[TM * 32];
    __shared__ alignas(16) _Float16 Bs[128 * 32];

    const int t    = threadIdx.x;
    const int lane = t & 63;
    const int wave = t >> 6;
    const int wm   = wave >> 1, wn = wave & 1;

    floatx4 acc[MI][4] = {};

    // B staging (fp16 weights, global_load_lds x2)
    const int rowL = t >> 2;
    const int kcol = (t & 3) * 8;
    const _Float16* gB = Bw + (size_t)(bn * 128 + rowL) * CH + kcol;
    _Float16* lB = &Bs[rowL * 32 + kcol];

    // A staging
    const _Float16* gA16 = nullptr; _Float16* lA16 = nullptr;
    const float* gA32 = nullptr; _Float16* lA32 = nullptr;
    if constexpr (AFP32) {
        const int arow = (TM == 128) ? (t >> 1) : (t >> 2);
        const int ac0  = (TM == 128) ? ((t & 1) * 16) : ((t & 3) * 8);
        gA32 = (const float*)Ap + (size_t)(bm * TM + arow) * CH + ac0;
        lA32 = &As[arow * 32 + ac0];
    } else {
        gA16 = (const _Float16*)Ap + (size_t)(bm * TM + rowL) * CH + kcol;
        lA16 = &As[rowL * 32 + kcol];
    }

    const int r0 = lane & 15;
    const int ko = (lane >> 4) * 8;

    for (int kt = 0; kt < CH / 32; ++kt) {
        if constexpr (AFP32) {
            const float* ga = gA32 + kt * 32;
            if constexpr (TM == 128) {
                float4 x0 = ((const float4*)ga)[0], x1 = ((const float4*)ga)[1];
                float4 x2 = ((const float4*)ga)[2], x3 = ((const float4*)ga)[3];
                H8 o0, o1;
                o0.p[0] = cvt2(x0.x, x0.y);
                o0.p[1] = cvt2(x0.z, x0.w);
                o0.p[2] = cvt2(x1.x, x1.y);
                o0.p[3] = cvt2(x1.z, x1.w);
                o1.p[0] = cvt2(x2.x, x2.y);
                o1.p[1] = cvt2(x2.z, x2.w);
                o1.p[2] = cvt2(x3.x, x3.y);
                o1.p[3] = cvt2(x3.z, x3.w);
                *(half8*)lA32       = o0.v;
                *(half8*)(lA32 + 8) = o1.v;
            } else {
                float4 x0 = ((const float4*)ga)[0], x1 = ((const float4*)ga)[1];
                H8 o0;
                o0.p[0] = cvt2(x0.x, x0.y);
                o0.p[1] = cvt2(x0.z, x0.w);
                o0.p[2] = cvt2(x1.x, x1.y);
                o0.p[3] = cvt2(x1.z, x1.w);
                *(half8*)lA32 = o0.v;
            }
        } else {
            const _Float16* a0 = gA16 + kt * 32;
            async16(a0, lA16);
            if constexpr (TM == 128) async16(a0 + 64 * CH, lA16 + 64 * 32);
        }
        const _Float16* b0 = gB + kt * 32;
        async16(b0,           lB);
        async16(b0 + 64 * CH, lB + 64 * 32);
        __syncthreads();

        half8 af[MI], bf[4];
        #pragma unroll
        for (int mi = 0; mi < MI; ++mi)
            af[mi] = *(const half8*)&As[(wm * (TM / 2) + mi * 16 + r0) * 32 + ko];
        #pragma unroll
        for (int ni = 0; ni < 4; ++ni)
            bf[ni] = *(const half8*)&Bs[(wn * 64 + ni * 16 + r0) * 32 + ko];
        #pragma unroll
        for (int mi = 0; mi < MI; ++mi)
            #pragma unroll
            for (int ni = 0; ni < 4; ++ni)
                acc[mi][ni] = __builtin_amdgcn_mfma_f32_16x16x32_f16(
                    af[mi], bf[ni], acc[mi][ni], 0, 0, 0);
        __syncthreads();
    }

    #pragma unroll
    for (int mi = 0; mi < MI; ++mi) {
        #pragma unroll
        for (int ni = 0; ni < 4; ++ni) {
            const int col = bn * 128 + wn * 64 + ni * 16 + (lane & 15);
            const float bv = bias[col];
            #pragma unroll
            for (int r = 0; r < 4; ++r) {
                const int row = bm * TM + wm * (TM / 2) + mi * 16 + (lane >> 4) * 4 + r;
                const float v = (acc[mi][ni][r] + bv) * oscale;
                if (OUTF16) ((_Float16*)outp)[(size_t)row * CH + col] = (_Float16)v;
                else        ((float*)outp)[(size_t)row * CH + col]    = v;
            }
        }
    }
}

template<int OUTF16, int TM, int AFP32>
__global__ __launch_bounds__(256) void gemm_k(
    const void* __restrict__ A, const _Float16* __restrict__ Bw,
    const float* __restrict__ bias, void* __restrict__ outp, float oscale)
{
    gemm_body<OUTF16, TM, AFP32>(A, Bw, bias, outp, oscale, blockIdx.x, blockIdx.y);
}

// K and V projections fused in one launch via blockIdx.z
__global__ __launch_bounds__(256) void gemm_kv(
    const float* __restrict__ keyp, const float* __restrict__ valp,
    const _Float16* __restrict__ w16, const float* __restrict__ bIn,
    _Float16* __restrict__ k16, _Float16* __restrict__ v16)
{
    const int z = blockIdx.z;
    gemm_body<1, 128, 1>(z ? (const void*)valp : (const void*)keyp,
                         w16 + (size_t)(z ? 1024 : 512) * 512,
                         bIn + (z ? 1024 : 512),
                         z ? (void*)v16 : (void*)k16, 1.0f,
                         blockIdx.x, blockIdx.y);
}

// ---------------- local attention: one block (256 thr) per query ----------------
__global__ __launch_bounds__(256) void attn_kernel(
    const _Float16* __restrict__ q16, const _Float16* __restrict__ k16,
    const _Float16* __restrict__ v16, const int* __restrict__ ipair,
    const int* __restrict__ ibatch, const int* __restrict__ kcnt,
    _Float16* __restrict__ op16, float* __restrict__ aout)
{
    __shared__ uint32_t vmask[LNB];       // row byte-offset | (masked<<31)
    __shared__ float    pls[LNB * 9];     // logits -> probs (stride 9)
    __shared__ __half2  pph[LNB * 9];     // probs pre-packed {p,p} fp16
    __shared__ float    part[4][CH];      // per-wave PV partials

    const int t = threadIdx.x;
    // XCD swizzle: batch b = n/512 -> XCD b (one batch's K+V fp16 fits one L2)
    const int n = ((blockIdx.x & 7) << 9) | (blockIdx.x >> 3);

    if (t < LNB) {
        const int idx = ipair[(size_t)n * LNB + t];
        const int b   = ibatch[n];
        int off = 0;
        for (int i = 0; i < b; ++i) off += kcnt[i];
        const uint32_t vo = (uint32_t)((idx < 0 ? 0 : (idx + off)) * (CH * 2));
        vmask[t] = vo | (idx < 0 ? 0x80000000u : 0u);
    }
    __syncthreads();

    const int lane = t & 63, wv = t >> 6;
    const int h    = lane >> 3;           // head for this lane
    const int l0   = wv * 24;             // wave's contiguous l-chunk

    // ---- phase 1: logits. lane owns dims [lane*8, +8); octet = one head.
    {
        const half8 qv = *(const half8*)(q16 + (size_t)n * CH + lane * 8);
        H8 qu; qu.v = qv;
        const char* kbase = (const char*)k16 + lane * 16;
        const int4* vb = (const int4*)&vmask[l0];
        for (int g = 0; g < 3; ++g) {
            const int4 w0 = vb[2 * g], w1 = vb[2 * g + 1];
            uint32_t vm8[8] = {(uint32_t)w0.x, (uint32_t)w0.y, (uint32_t)w0.z, (uint32_t)w0.w,
                               (uint32_t)w1.x, (uint32_t)w1.y, (uint32_t)w1.z, (uint32_t)w1.w};
            #pragma unroll
            for (int j = 0; j < 8; ++j) {
                const uint32_t vms = __builtin_amdgcn_readfirstlane(vm8[j]);
                H8 ku; ku.v = *(const half8*)(kbase + (vms & 0x7fffffffu));
                float acc = 0.f;
                #pragma unroll
                for (int u = 0; u < 4; ++u)
                    acc = __builtin_amdgcn_fdot2(qu.p[u], ku.p[u], acc, false);
                acc = octet_sum(acc);
                if ((lane & 7) == 0)
                    pls[(l0 + g * 8 + j) * 9 + h] = (vms & 0x80000000u) ? -1e30f : acc;
            }
        }
    }
    __syncthreads();

    // ---- phase 2: softmax over L per head (hh = t>>5, j = t&31)
    {
        const int hh = t >> 5, j = t & 31;
        const float v0 = pls[j * 9 + hh];
        const float v1 = pls[(j + 32) * 9 + hh];
        const float v2 = pls[(j + 64) * 9 + hh];
        float m = fmaxf(v0, fmaxf(v1, v2));
        #pragma unroll
        for (int s = 16; s >= 1; s >>= 1) m = fmaxf(m, __shfl_xor(m, s, 32));
        const float e0 = __expf(v0 - m), e1 = __expf(v1 - m), e2 = __expf(v2 - m);
        float ssum = e0 + e1 + e2;
        #pragma unroll
        for (int s = 16; s >= 1; s >>= 1) ssum += __shfl_xor(ssum, s, 32);
        const float rinv = 1.0f / ssum;
        const float p0 = e0 * rinv, p1 = e1 * rinv, p2 = e2 * rinv;
        pls[j * 9 + hh]        = p0;
        pls[(j + 32) * 9 + hh] = p1;
        pls[(j + 64) * 9 + hh] = p2;
        pph[j * 9 + hh]        = __half2half2(__float2half_rn(p0));
        pph[(j + 32) * 9 + hh] = __half2half2(__float2half_rn(p1));
        pph[(j + 64) * 9 + hh] = __half2half2(__float2half_rn(p2));
    }
    __syncthreads();

    // ---- attn_mean (output 1)
    if (t < LNB) {
        float s = 0.f;
        #pragma unroll
        for (int u = 0; u < NH; ++u) s += pls[t * 9 + u];
        aout[(size_t)n * LNB + t] = s * (1.0f / NH);
    }

    // ---- phase 3: PV. wave owns l in [l0, l0+24), lane owns 8 dims.
    // fp16 pk_fma accumulate in 8-l groups, dumped to f32.
    {
        float accf[8] = {};
        const char* vbase = (const char*)v16 + lane * 16;
        const int4* vb = (const int4*)&vmask[l0];
        const __half2 hz = __half2half2(__float2half_rn(0.f));
        for (int g = 0; g < 3; ++g) {
            const int4 w0 = vb[2 * g], w1 = vb[2 * g + 1];
            uint32_t vm8[8] = {(uint32_t)w0.x, (uint32_t)w0.y, (uint32_t)w0.z, (uint32_t)w0.w,
                               (uint32_t)w1.x, (uint32_t)w1.y, (uint32_t)w1.z, (uint32_t)w1.w};
            __half2 a0 = hz, a1 = hz, a2 = hz, a3 = hz;
            #pragma unroll
            for (int j = 0; j < 8; ++j) {
                const uint32_t vms = __builtin_amdgcn_readfirstlane(vm8[j]);
                const half8 vv = *(const half8*)(vbase + (vms & 0x7fffffffu));
                union { half8 v; __half2 q[4]; } vu; vu.v = vv;
                const __half2 pp = pph[(l0 + g * 8 + j) * 9 + h];
                a0 = __hfma2(pp, vu.q[0], a0);
                a1 = __hfma2(pp, vu.q[1], a1);
                a2 = __hfma2(pp, vu.q[2], a2);
                a3 = __hfma2(pp, vu.q[3], a3);
            }
            float2 f;
            f = __half22float2(a0); accf[0] += f.x; accf[1] += f.y;
            f = __half22float2(a1); accf[2] += f.x; accf[3] += f.y;
            f = __half22float2(a2); accf[4] += f.x; accf[5] += f.y;
            f = __half22float2(a3); accf[6] += f.x; accf[7] += f.y;
        }
        floatx4 lo, hi;
        #pragma unroll
        for (int u = 0; u < 4; ++u) { lo[u] = accf[u]; hi[u] = accf[u + 4]; }
        *(floatx4*)&part[wv][lane * 8]     = lo;
        *(floatx4*)&part[wv][lane * 8 + 4] = hi;
    }
    __syncthreads();

    // ---- final cross-wave reduce: thread t owns dims 2t, 2t+1
    {
        const int c = t * 2;
        floatx2 s = *(const floatx2*)&part[0][c];
        #pragma unroll
        for (int w = 1; w < 4; ++w) {
            floatx2 pw = *(const floatx2*)&part[w][c];
            s[0] += pw[0]; s[1] += pw[1];
        }
        h2 o; o[0] = (_Float16)s[0]; o[1] = (_Float16)s[1];
        *(h2*)&op16[(size_t)n * CH + c] = o;
    }
}

extern "C" void kernel_launch(void* const* d_in, const int* in_sizes, int n_in,
                              void* d_out, int out_size, void* d_ws, size_t ws_size,
                              hipStream_t stream)
{
    const float* query = (const float*)d_in[0];
    const float* key   = (const float*)d_in[1];
    const float* value = (const float*)d_in[2];
    const int*   ipair = (const int*)d_in[3];
    const int*   kcnt  = (const int*)d_in[5];
    const int*   ibat  = (const int*)d_in[6];
    const float* wIn   = (const float*)d_in[7];
    const float* bIn   = (const float*)d_in[8];
    const float* wOut  = (const float*)d_in[9];
    const float* bOut  = (const float*)d_in[10];

    float* out  = (float*)d_out;
    float* aout = out + (size_t)N_Q * CH;

    char* ws = (char*)d_ws;
    _Float16* w16  = (_Float16*)(ws);                // in-proj weights fp16 (1.5MB)
    _Float16* wo16 = (_Float16*)(ws + 1572864);      // out-proj weights fp16 (contiguous)
    _Float16* q16  = (_Float16*)(ws + 2097152);      // 4MB
    _Float16* k16  = (_Float16*)(ws + 6291456);      // 16MB
    _Float16* v16  = (_Float16*)(ws + 23068672);     // 16MB
    _Float16* op16 = (_Float16*)(ws + 39845888);     // 4MB

    // one fused weight convert (wIn ++ wOut -> w16 ++ wo16)
    cvt_weights<<<1024, 256, 0, stream>>>(wIn, wOut, w16);

    // projections with fused fp32->fp16 A staging
    gemm_k<1, 64, 1><<<dim3(64, 4), 256, 0, stream>>>(query, w16, bIn, q16, 0.125f);
    gemm_kv<<<dim3(128, 4, 2), 256, 0, stream>>>(key, value, w16, bIn, k16, v16);

    attn_kernel<<<4096, 256, 0, stream>>>(q16, k16, v16, ipair, ibat, kcnt, op16, aout);

    gemm_k<0, 64, 0><<<dim3(64, 4), 256, 0, stream>>>(op16, wo16, bOut, d_out, 1.0f);
}